// Round 8
// baseline (1135.459 us; speedup 1.0000x reference)
//
#include <hip/hip_runtime.h>
#include <hip/hip_bf16.h>
#include <math.h>

// B=32768, L=24, H=64, V=64
// ===== DIAGNOSTIC BUILD: kernels repeat their (idempotent) work REP_* times
// so they rise above the ~39us harness fill kernels and surface in rocprof
// top-5 with real counters. True per-kernel wall = (End-Start)/REP.
#define REP_TAB  32
#define REP_GW   32
#define REP_SCAN 8

#define B_SZ 32768
#define L_SZ 24
#define H_SZ 64
#define V_SZ 64

// ws layout (dword offsets)
#define KN_O    0        // kn[64][64] f32
#define WK_O    4096     // Wk[64][64] f32
#define G_O     8192     // G[64][64] f32
#define WKTH_O  12288    // WkT hi bf16 [64][72]
#define WKTL_O  14592    // WkT lo bf16 [64][72]
#define TAIL_O  16896    // nrm[64] | b2[64] | cf[32]
#define WS_DW   17056

// scan LDS layout (dwords)
#define G_L     0
#define WKTH_L  4096
#define WKTL_L  6400
#define TAIL_L  8704
#define W32_L   8864     // W accum f32 [64][64]
#define WH_L    12960    // W hi bf16 [64][72]
#define WL_L    15264    // W lo bf16 [64][72]
#define LDS_DW  17568    // 70.3 KB -> 2 blocks/CU

typedef __attribute__((ext_vector_type(8))) short short8v;
typedef __attribute__((ext_vector_type(4))) float f32x4;

static __device__ __forceinline__ unsigned short bf_hi(float x) {
  const unsigned b = __float_as_uint(x);
  return (unsigned short)((b + 0x7FFF + ((b >> 16) & 1)) >> 16);  // RNE
}

// ---------------------------------------------------------------------------
// Kernel A: table build (validated R3-R7). DIAG: x REP_TAB.
// ---------------------------------------------------------------------------
__global__ __launch_bounds__(64) void k_tab(
    const float* __restrict__ embed, const float* __restrict__ w1, const float* __restrict__ b1,
    const float* __restrict__ w2, const float* __restrict__ b2,
    const float* __restrict__ ln_g, const float* __restrict__ ln_b,
    const float* __restrict__ rp_w, const float* __restrict__ rp_b,
    const float* __restrict__ out_w, const float* __restrict__ out_b,
    const float* __restrict__ alpha_logits, float* __restrict__ ws_in)
{
  const int v = blockIdx.x;
  const int j = threadIdx.x;
  float* ws = ws_in;

  #pragma unroll 1
  for (int rep = 0; rep < REP_TAB; ++rep) {
    asm volatile("" : "+s"(ws));   // defeat CSE/hoisting across reps
    if (v < V_SZ) {
      const float ev = embed[v * H_SZ + j];
      float h0 = b1[j], h1 = b1[j + 64];
      #pragma unroll
      for (int k = 0; k < H_SZ; ++k) {
        const float ek = __shfl(ev, k);
        h0 = fmaf(ek, w1[k * 128 + j], h0);
        h1 = fmaf(ek, w1[k * 128 + 64 + j], h1);
      }
      h0 = fmaxf(h0, 0.0f);
      h1 = fmaxf(h1, 0.0f);
      float x = ev + b2[j];
      #pragma unroll
      for (int k = 0; k < H_SZ; ++k) {
        x = fmaf(__shfl(h0, k), w2[k * H_SZ + j], x);
        x = fmaf(__shfl(h1, k), w2[(k + 64) * H_SZ + j], x);
      }
      float mu = x;
      #pragma unroll
      for (int m = 1; m < 64; m <<= 1) mu += __shfl_xor(mu, m);
      mu *= (1.0f / 64.0f);
      const float dv = x - mu;
      float var = dv * dv;
      #pragma unroll
      for (int m = 1; m < 64; m <<= 1) var += __shfl_xor(var, m);
      var *= (1.0f / 64.0f);
      const float y = dv * rsqrtf(var + 1e-5f) * ln_g[j] + ln_b[j];
      float n2 = y * y;
      #pragma unroll
      for (int m = 1; m < 64; m <<= 1) n2 += __shfl_xor(n2, m);
      const float nrm = sqrtf(n2);
      const float rn = 1.0f / fmaxf(nrm, 1e-12f);
      ws[KN_O + v * H_SZ + j] = y * rn;
      if (j == 0) ws[TAIL_O + v] = nrm;
      float t1 = 0.0f;
      #pragma unroll
      for (int k = 0; k < H_SZ; ++k) t1 = fmaf(__shfl(y, k), rp_w[k * H_SZ + j], t1);
      float wk = 0.0f;
      #pragma unroll
      for (int k = 0; k < H_SZ; ++k) wk = fmaf(__shfl(t1, k), out_w[k * V_SZ + j], wk);
      ws[WK_O + v * H_SZ + j] = wk;
    } else {
      float s = out_b[j];
      #pragma unroll
      for (int k = 0; k < H_SZ; ++k) s = fmaf(rp_b[k], out_w[k * V_SZ + j], s);
      ws[TAIL_O + 64 + j] = s;
      if (j < 32) {
        float cf = 0.0f;
        if (j < L_SZ - 1) {
          const float a = 1.0f / (1.0f + expf(-alpha_logits[j])) * 0.49f + 0.5f;
          cf = 1.0f - a;
        }
        ws[TAIL_O + 128 + j] = cf;
      }
    }
  }
}

// ---------------------------------------------------------------------------
// Kernel B: Gram row + WkT bf16 split (validated R7). DIAG: x REP_GW.
// ---------------------------------------------------------------------------
__global__ __launch_bounds__(64) void k_gw(float* __restrict__ ws_in)
{
  const int u = blockIdx.x;
  const int j = threadIdx.x;
  float* ws = ws_in;

  #pragma unroll 1
  for (int rep = 0; rep < REP_GW; ++rep) {
    asm volatile("" : "+s"(ws));
    const float a = ws[KN_O + u * H_SZ + j];
    float r[64];
    const float4* rp = (const float4*)(ws + KN_O + j * H_SZ);
    #pragma unroll
    for (int i = 0; i < 16; ++i) {
      const float4 f = rp[i];
      r[4 * i] = f.x; r[4 * i + 1] = f.y; r[4 * i + 2] = f.z; r[4 * i + 3] = f.w;
    }
    float s = 0.0f;
    #pragma unroll
    for (int k = 0; k < 64; ++k) s = fmaf(__shfl(a, k), r[k], s);
    ws[G_O + u * H_SZ + j] = s;

    const float x = ws[WK_O + j * H_SZ + u];
    const unsigned short hi = bf_hi(x);
    const float fhi = __uint_as_float((unsigned)hi << 16);
    const unsigned short lo = bf_hi(x - fhi);
    unsigned short* wsu = (unsigned short*)ws;
    wsu[WKTH_O * 2 + u * 72 + j] = hi;
    wsu[WKTL_O * 2 + u * 72 + j] = lo;
  }
}

// ---------------------------------------------------------------------------
// Kernel C: scan (validated R7). DIAG: x REP_SCAN (full restage+recompute).
// ---------------------------------------------------------------------------
__global__ __launch_bounds__(256) void k_scan(
    const int* __restrict__ seq_in, const float* __restrict__ ws_in, float* __restrict__ out_in)
{
  __shared__ float lds[LDS_DW];
  const int tid = threadIdx.x;
  const int lane = tid & 63;
  const int wv = tid >> 6;
  const int batch0 = blockIdx.x * 64;

  const int* seq = seq_in;
  const float* ws = ws_in;
  float* out = out_in;

  #pragma unroll 1
  for (int rep = 0; rep < REP_SCAN; ++rep) {
    asm volatile("" : "+s"(seq), "+s"(ws), "+s"(out));

    const float4* ws4 = (const float4*)ws;
    float4* l4 = (float4*)lds;
    for (int i = tid; i < (WS_DW - 8192) / 4; i += 256) l4[i] = ws4[2048 + i];
    const float4 z4 = {0.f, 0.f, 0.f, 0.f};
    for (int i = tid; i < 1024; i += 256) ((float4*)(lds + W32_L))[i] = z4;
    __syncthreads();

    const float* Gt = lds + G_L;

    // ---- Phase A ----
    if (lane < 16) {
      const int ab = wv * 16 + lane;
      int g[24];
      const int4* sp = (const int4*)(seq + (batch0 + ab) * L_SZ);
      #pragma unroll
      for (int i = 0; i < 6; ++i) {
        const int4 t4 = sp[i];
        g[4 * i] = t4.x; g[4 * i + 1] = t4.y; g[4 * i + 2] = t4.z; g[4 * i + 3] = t4.w;
      }
      const int q = g[23];
      const float nl = lds[TAIL_L + q];
      float cfv[24];
      #pragma unroll
      for (int i = 0; i < 6; ++i) {
        const float4 f = ((const float4*)(lds + TAIL_L + 128))[i];
        cfv[4 * i] = f.x; cfv[4 * i + 1] = f.y; cfv[4 * i + 2] = f.z; cfv[4 * i + 3] = f.w;
      }
      float P[23], carr[23];
      #pragma unroll
      for (int t = 0; t < 23; ++t) P[t] = 0.0f;
      #pragma unroll
      for (int s = 22; s >= 0; --s) {
        const float base = nl * Gt[(g[s] << 6) + q];
        const float cs = cfv[s] * (base - P[s]);
        carr[s] = cs;
        #pragma unroll
        for (int t = 0; t < s; ++t)
          P[t] = fmaf(cs, Gt[(g[t] << 6) + g[s]], P[t]);
      }
      float* wrow = lds + W32_L + ab * 64;
      #pragma unroll
      for (int t = 0; t < 23; ++t)
        atomicAdd(&wrow[g[t]], carr[t]);
    }
    __syncthreads();

    // ---- Convert W32 -> WH/WL ----
    {
      const int c4 = (lane & 15) * 4;
      unsigned short* whp = (unsigned short*)(lds + WH_L);
      unsigned short* wlp = (unsigned short*)(lds + WL_L);
      #pragma unroll
      for (int i = 0; i < 4; ++i) {
        const int row = wv * 16 + (lane >> 4) + i * 4;
        const float4 f = *(const float4*)(lds + W32_L + row * 64 + c4);
        ushort4 h, l2;
        h.x = bf_hi(f.x); h.y = bf_hi(f.y); h.z = bf_hi(f.z); h.w = bf_hi(f.w);
        l2.x = bf_hi(f.x - __uint_as_float((unsigned)h.x << 16));
        l2.y = bf_hi(f.y - __uint_as_float((unsigned)h.y << 16));
        l2.z = bf_hi(f.z - __uint_as_float((unsigned)h.z << 16));
        l2.w = bf_hi(f.w - __uint_as_float((unsigned)h.w << 16));
        *(ushort4*)(whp + row * 72 + c4) = h;
        *(ushort4*)(wlp + row * 72 + c4) = l2;
      }
    }
    __syncthreads();

    // ---- Phase B: MFMA ----
    {
      const int cl = lane & 15;
      const int q4 = lane >> 4;
      const unsigned short* whp = (const unsigned short*)(lds + WH_L);
      const unsigned short* wlp = (const unsigned short*)(lds + WL_L);
      const unsigned short* bhp = (const unsigned short*)(lds + WKTH_L);
      const unsigned short* blp = (const unsigned short*)(lds + WKTL_L);

      const int arow = wv * 16 + cl;
      const short8v ah0 = *(const short8v*)(whp + arow * 72 + q4 * 8);
      const short8v ah1 = *(const short8v*)(whp + arow * 72 + 32 + q4 * 8);
      const short8v al0 = *(const short8v*)(wlp + arow * 72 + q4 * 8);
      const short8v al1 = *(const short8v*)(wlp + arow * 72 + 32 + q4 * 8);

      #pragma unroll
      for (int ct = 0; ct < 4; ++ct) {
        const int col = ct * 16 + cl;
        const short8v bh0 = *(const short8v*)(bhp + col * 72 + q4 * 8);
        const short8v bh1 = *(const short8v*)(bhp + col * 72 + 32 + q4 * 8);
        const short8v bl0 = *(const short8v*)(blp + col * 72 + q4 * 8);
        const short8v bl1 = *(const short8v*)(blp + col * 72 + 32 + q4 * 8);
        const float b2v = lds[TAIL_L + 64 + col];
        f32x4 acc = {b2v, b2v, b2v, b2v};
        acc = __builtin_amdgcn_mfma_f32_16x16x32_bf16(ah0, bh0, acc, 0, 0, 0);
        acc = __builtin_amdgcn_mfma_f32_16x16x32_bf16(ah1, bh1, acc, 0, 0, 0);
        acc = __builtin_amdgcn_mfma_f32_16x16x32_bf16(al0, bh0, acc, 0, 0, 0);
        acc = __builtin_amdgcn_mfma_f32_16x16x32_bf16(al1, bh1, acc, 0, 0, 0);
        acc = __builtin_amdgcn_mfma_f32_16x16x32_bf16(ah0, bl0, acc, 0, 0, 0);
        acc = __builtin_amdgcn_mfma_f32_16x16x32_bf16(ah1, bl1, acc, 0, 0, 0);
        #pragma unroll
        for (int rr = 0; rr < 4; ++rr)
          out[(batch0 + wv * 16 + q4 * 4 + rr) * V_SZ + col] = acc[rr];
      }
    }
    __syncthreads();   // protect next rep's W32 re-zero
  }
}

// ---------------------------------------------------------------------------
extern "C" void kernel_launch(void* const* d_in, const int* in_sizes, int n_in,
                              void* d_out, int out_size, void* d_ws, size_t ws_size,
                              hipStream_t stream)
{
  const int*   seq          = (const int*)d_in[0];
  const float* embed        = (const float*)d_in[1];
  const float* w1           = (const float*)d_in[2];
  const float* b1           = (const float*)d_in[3];
  const float* w2           = (const float*)d_in[4];
  const float* b2           = (const float*)d_in[5];
  const float* ln_g         = (const float*)d_in[6];
  const float* ln_b         = (const float*)d_in[7];
  const float* rp_w         = (const float*)d_in[8];
  const float* rp_b         = (const float*)d_in[9];
  const float* out_w        = (const float*)d_in[10];
  const float* out_b        = (const float*)d_in[11];
  const float* alpha_logits = (const float*)d_in[12];
  float* ws   = (float*)d_ws;
  float* outp = (float*)d_out;

  hipLaunchKernelGGL(k_tab, dim3(V_SZ + 1), dim3(64), 0, stream,
                     embed, w1, b1, w2, b2, ln_g, ln_b,
                     rp_w, rp_b, out_w, out_b, alpha_logits, ws);
  hipLaunchKernelGGL(k_gw, dim3(V_SZ), dim3(64), 0, stream, ws);
  hipLaunchKernelGGL(k_scan, dim3(B_SZ / 64), dim3(256), 0, stream,
                     seq, ws, outp);
}

// Round 9
// 29.916 us; speedup vs baseline: 37.9545x; 37.9545x over previous
//
#include <hip/hip_runtime.h>
#include <hip/hip_bf16.h>
#include <math.h>

// B=32768, L=24, H=64, V=64
#define B_SZ 32768
#define L_SZ 24
#define H_SZ 64
#define V_SZ 64

// ws layout (dword offsets)
#define KN_O    0        // kn[64][64] f32
#define WK_O    4096     // Wk[64][64] f32
#define G_O     8192     // G[64][64] f32
#define WKTH_O  12288    // WkT hi bf16 [64][72]
#define WKTL_O  14592    // WkT lo bf16 [64][72]
#define TAIL_O  16896    // nrm[64] | b2[64] | cf[32]
#define WS_DW   17056

// k_scan LDS layout (dwords)
#define G_L     0
#define WKTH_L  4096
#define WKTL_L  6400
#define TAIL_L  8704
#define W32_L   8864     // W accum f32 [64][64]
#define WH_L    12960    // W hi bf16 [64][72]
#define WL_L    15264    // W lo bf16 [64][72]
#define LDS_DW  17568    // 70.3 KB -> 2 blocks/CU

// k_tab LDS layout (dwords): staged weights
#define W1_T    0        // w1[64][128]
#define W2_T    8192     // w2[128][64]
#define RP_T    16384    // rp_w[64][64]
#define OW_T    20480    // out_w[64][64]
#define TAB_DW  24576    // 96 KB

typedef __attribute__((ext_vector_type(8))) short short8v;
typedef __attribute__((ext_vector_type(4))) float f32x4;

static __device__ __forceinline__ unsigned short bf_hi(float x) {
  const unsigned b = __float_as_uint(x);
  return (unsigned short)((b + 0x7FFF + ((b >> 16) & 1)) >> 16);  // RNE
}

// ---------------------------------------------------------------------------
// Kernel A v2: table build, latency-fixed. Grid 17 x 256.
// Blocks 0..15: stage w1|w2|rp_w|out_w into LDS (24 float4 loads/thread, one
// latency round-trip), then wave w computes vocab row 4*blk+w with the
// validated R1-R7 shfl-matvec sequence (LDS-sourced, identical FMA order).
// Block 16: bias2 + cf (64 threads).
// ---------------------------------------------------------------------------
__global__ __launch_bounds__(256) void k_tab(
    const float* __restrict__ embed, const float* __restrict__ w1, const float* __restrict__ b1,
    const float* __restrict__ w2, const float* __restrict__ b2,
    const float* __restrict__ ln_g, const float* __restrict__ ln_b,
    const float* __restrict__ rp_w, const float* __restrict__ rp_b,
    const float* __restrict__ out_w, const float* __restrict__ out_b,
    const float* __restrict__ alpha_logits, float* __restrict__ ws)
{
  __shared__ float tabL[TAB_DW];
  const int tid = threadIdx.x;

  if (blockIdx.x < 16) {
    // ---- stage all weights: issue 24 float4 loads, then write to LDS ----
    {
      const float4* s1 = (const float4*)w1;
      const float4* s2 = (const float4*)w2;
      const float4* sr = (const float4*)rp_w;
      const float4* so = (const float4*)out_w;
      float4 r1[8], r2[8], rr[4], ro[4];
      #pragma unroll
      for (int i = 0; i < 8; ++i) r1[i] = s1[tid + 256 * i];
      #pragma unroll
      for (int i = 0; i < 8; ++i) r2[i] = s2[tid + 256 * i];
      #pragma unroll
      for (int i = 0; i < 4; ++i) rr[i] = sr[tid + 256 * i];
      #pragma unroll
      for (int i = 0; i < 4; ++i) ro[i] = so[tid + 256 * i];
      #pragma unroll
      for (int i = 0; i < 8; ++i) ((float4*)(tabL + W1_T))[tid + 256 * i] = r1[i];
      #pragma unroll
      for (int i = 0; i < 8; ++i) ((float4*)(tabL + W2_T))[tid + 256 * i] = r2[i];
      #pragma unroll
      for (int i = 0; i < 4; ++i) ((float4*)(tabL + RP_T))[tid + 256 * i] = rr[i];
      #pragma unroll
      for (int i = 0; i < 4; ++i) ((float4*)(tabL + OW_T))[tid + 256 * i] = ro[i];
    }
    __syncthreads();

    const int j = tid & 63;
    const int v = blockIdx.x * 4 + (tid >> 6);   // wave -> vocab row
    const float* w1L = tabL + W1_T;
    const float* w2L = tabL + W2_T;
    const float* rpL = tabL + RP_T;
    const float* owL = tabL + OW_T;

    const float ev = embed[v * H_SZ + j];
    float h0 = b1[j], h1 = b1[j + 64];
    #pragma unroll
    for (int k = 0; k < H_SZ; ++k) {
      const float ek = __shfl(ev, k);
      h0 = fmaf(ek, w1L[k * 128 + j], h0);
      h1 = fmaf(ek, w1L[k * 128 + 64 + j], h1);
    }
    h0 = fmaxf(h0, 0.0f);
    h1 = fmaxf(h1, 0.0f);
    float x = ev + b2[j];
    #pragma unroll
    for (int k = 0; k < H_SZ; ++k) {
      x = fmaf(__shfl(h0, k), w2L[k * H_SZ + j], x);
      x = fmaf(__shfl(h1, k), w2L[(k + 64) * H_SZ + j], x);
    }
    float mu = x;
    #pragma unroll
    for (int m = 1; m < 64; m <<= 1) mu += __shfl_xor(mu, m);
    mu *= (1.0f / 64.0f);
    const float dv = x - mu;
    float var = dv * dv;
    #pragma unroll
    for (int m = 1; m < 64; m <<= 1) var += __shfl_xor(var, m);
    var *= (1.0f / 64.0f);
    const float y = dv * rsqrtf(var + 1e-5f) * ln_g[j] + ln_b[j];
    float n2 = y * y;
    #pragma unroll
    for (int m = 1; m < 64; m <<= 1) n2 += __shfl_xor(n2, m);
    const float nrm = sqrtf(n2);
    const float rn = 1.0f / fmaxf(nrm, 1e-12f);
    ws[KN_O + v * H_SZ + j] = y * rn;
    if (j == 0) ws[TAIL_O + v] = nrm;
    float t1 = 0.0f;
    #pragma unroll
    for (int k = 0; k < H_SZ; ++k) t1 = fmaf(__shfl(y, k), rpL[k * H_SZ + j], t1);
    float wk = 0.0f;
    #pragma unroll
    for (int k = 0; k < H_SZ; ++k) wk = fmaf(__shfl(t1, k), owL[k * H_SZ + j], wk);
    ws[WK_O + v * H_SZ + j] = wk;
  } else if (tid < 64) {
    const int j = tid;
    float s = out_b[j];
    #pragma unroll
    for (int k = 0; k < H_SZ; ++k) s = fmaf(rp_b[k], out_w[k * V_SZ + j], s);
    ws[TAIL_O + 64 + j] = s;
    if (j < 32) {
      float cf = 0.0f;
      if (j < L_SZ - 1) {
        const float a = 1.0f / (1.0f + expf(-alpha_logits[j])) * 0.49f + 0.5f;
        cf = 1.0f - a;
      }
      ws[TAIL_O + 128 + j] = cf;
    }
  }
}

// ---------------------------------------------------------------------------
// Kernel B: Gram row + WkT bf16 split (validated R7, unchanged).
// ---------------------------------------------------------------------------
__global__ __launch_bounds__(64) void k_gw(float* __restrict__ ws)
{
  const int u = blockIdx.x;
  const int j = threadIdx.x;
  const float a = ws[KN_O + u * H_SZ + j];
  float r[64];
  const float4* rp = (const float4*)(ws + KN_O + j * H_SZ);
  #pragma unroll
  for (int i = 0; i < 16; ++i) {
    const float4 f = rp[i];
    r[4 * i] = f.x; r[4 * i + 1] = f.y; r[4 * i + 2] = f.z; r[4 * i + 3] = f.w;
  }
  float s = 0.0f;
  #pragma unroll
  for (int k = 0; k < 64; ++k) s = fmaf(__shfl(a, k), r[k], s);
  ws[G_O + u * H_SZ + j] = s;

  const float x = ws[WK_O + j * H_SZ + u];
  const unsigned short hi = bf_hi(x);
  const float fhi = __uint_as_float((unsigned)hi << 16);
  const unsigned short lo = bf_hi(x - fhi);
  unsigned short* wsu = (unsigned short*)ws;
  wsu[WKTH_O * 2 + u * 72 + j] = hi;
  wsu[WKTL_O * 2 + u * 72 + j] = lo;
}

// ---------------------------------------------------------------------------
// Kernel C: scan (validated R7, unchanged). 256 thr, 64 batches/block,
// grid 512. Phase A: scalar Gram recursion + ds_add scatter into W.
// Phase B: out = b2 + W @ WkT via split-precision MFMA.
// ---------------------------------------------------------------------------
__global__ __launch_bounds__(256) void k_scan(
    const int* __restrict__ seq, const float* __restrict__ ws, float* __restrict__ out)
{
  __shared__ float lds[LDS_DW];
  const int tid = threadIdx.x;
  const float4* ws4 = (const float4*)ws;
  float4* l4 = (float4*)lds;
  for (int i = tid; i < (WS_DW - 8192) / 4; i += 256) l4[i] = ws4[2048 + i];
  const float4 z4 = {0.f, 0.f, 0.f, 0.f};
  for (int i = tid; i < 1024; i += 256) ((float4*)(lds + W32_L))[i] = z4;
  __syncthreads();

  const int lane = tid & 63;
  const int wv = tid >> 6;
  const int batch0 = blockIdx.x * 64;
  const float* Gt = lds + G_L;

  // ---- Phase A ----
  if (lane < 16) {
    const int ab = wv * 16 + lane;
    int g[24];
    const int4* sp = (const int4*)(seq + (batch0 + ab) * L_SZ);
    #pragma unroll
    for (int i = 0; i < 6; ++i) {
      const int4 t4 = sp[i];
      g[4 * i] = t4.x; g[4 * i + 1] = t4.y; g[4 * i + 2] = t4.z; g[4 * i + 3] = t4.w;
    }
    const int q = g[23];
    const float nl = lds[TAIL_L + q];
    float cfv[24];
    #pragma unroll
    for (int i = 0; i < 6; ++i) {
      const float4 f = ((const float4*)(lds + TAIL_L + 128))[i];
      cfv[4 * i] = f.x; cfv[4 * i + 1] = f.y; cfv[4 * i + 2] = f.z; cfv[4 * i + 3] = f.w;
    }
    float P[23], carr[23];
    #pragma unroll
    for (int t = 0; t < 23; ++t) P[t] = 0.0f;
    #pragma unroll
    for (int s = 22; s >= 0; --s) {
      const float base = nl * Gt[(g[s] << 6) + q];
      const float cs = cfv[s] * (base - P[s]);
      carr[s] = cs;
      #pragma unroll
      for (int t = 0; t < s; ++t)
        P[t] = fmaf(cs, Gt[(g[t] << 6) + g[s]], P[t]);
    }
    float* wrow = lds + W32_L + ab * 64;
    #pragma unroll
    for (int t = 0; t < 23; ++t)
      atomicAdd(&wrow[g[t]], carr[t]);
  }
  __syncthreads();

  // ---- Convert W32 -> WH/WL ----
  {
    const int c4 = (lane & 15) * 4;
    unsigned short* whp = (unsigned short*)(lds + WH_L);
    unsigned short* wlp = (unsigned short*)(lds + WL_L);
    #pragma unroll
    for (int i = 0; i < 4; ++i) {
      const int row = wv * 16 + (lane >> 4) + i * 4;
      const float4 f = *(const float4*)(lds + W32_L + row * 64 + c4);
      ushort4 h, l2;
      h.x = bf_hi(f.x); h.y = bf_hi(f.y); h.z = bf_hi(f.z); h.w = bf_hi(f.w);
      l2.x = bf_hi(f.x - __uint_as_float((unsigned)h.x << 16));
      l2.y = bf_hi(f.y - __uint_as_float((unsigned)h.y << 16));
      l2.z = bf_hi(f.z - __uint_as_float((unsigned)h.z << 16));
      l2.w = bf_hi(f.w - __uint_as_float((unsigned)h.w << 16));
      *(ushort4*)(whp + row * 72 + c4) = h;
      *(ushort4*)(wlp + row * 72 + c4) = l2;
    }
  }
  __syncthreads();

  // ---- Phase B: MFMA ----
  {
    const int cl = lane & 15;
    const int q4 = lane >> 4;
    const unsigned short* whp = (const unsigned short*)(lds + WH_L);
    const unsigned short* wlp = (const unsigned short*)(lds + WL_L);
    const unsigned short* bhp = (const unsigned short*)(lds + WKTH_L);
    const unsigned short* blp = (const unsigned short*)(lds + WKTL_L);

    const int arow = wv * 16 + cl;
    const short8v ah0 = *(const short8v*)(whp + arow * 72 + q4 * 8);
    const short8v ah1 = *(const short8v*)(whp + arow * 72 + 32 + q4 * 8);
    const short8v al0 = *(const short8v*)(wlp + arow * 72 + q4 * 8);
    const short8v al1 = *(const short8v*)(wlp + arow * 72 + 32 + q4 * 8);

    #pragma unroll
    for (int ct = 0; ct < 4; ++ct) {
      const int col = ct * 16 + cl;
      const short8v bh0 = *(const short8v*)(bhp + col * 72 + q4 * 8);
      const short8v bh1 = *(const short8v*)(bhp + col * 72 + 32 + q4 * 8);
      const short8v bl0 = *(const short8v*)(blp + col * 72 + q4 * 8);
      const short8v bl1 = *(const short8v*)(blp + col * 72 + 32 + q4 * 8);
      const float b2v = lds[TAIL_L + 64 + col];
      f32x4 acc = {b2v, b2v, b2v, b2v};
      acc = __builtin_amdgcn_mfma_f32_16x16x32_bf16(ah0, bh0, acc, 0, 0, 0);
      acc = __builtin_amdgcn_mfma_f32_16x16x32_bf16(ah1, bh1, acc, 0, 0, 0);
      acc = __builtin_amdgcn_mfma_f32_16x16x32_bf16(al0, bh0, acc, 0, 0, 0);
      acc = __builtin_amdgcn_mfma_f32_16x16x32_bf16(al1, bh1, acc, 0, 0, 0);
      acc = __builtin_amdgcn_mfma_f32_16x16x32_bf16(ah0, bl0, acc, 0, 0, 0);
      acc = __builtin_amdgcn_mfma_f32_16x16x32_bf16(ah1, bl1, acc, 0, 0, 0);
      #pragma unroll
      for (int rr = 0; rr < 4; ++rr)
        out[(batch0 + wv * 16 + q4 * 4 + rr) * V_SZ + col] = acc[rr];
    }
  }
}

// ---------------------------------------------------------------------------
extern "C" void kernel_launch(void* const* d_in, const int* in_sizes, int n_in,
                              void* d_out, int out_size, void* d_ws, size_t ws_size,
                              hipStream_t stream)
{
  const int*   seq          = (const int*)d_in[0];
  const float* embed        = (const float*)d_in[1];
  const float* w1           = (const float*)d_in[2];
  const float* b1           = (const float*)d_in[3];
  const float* w2           = (const float*)d_in[4];
  const float* b2           = (const float*)d_in[5];
  const float* ln_g         = (const float*)d_in[6];
  const float* ln_b         = (const float*)d_in[7];
  const float* rp_w         = (const float*)d_in[8];
  const float* rp_b         = (const float*)d_in[9];
  const float* out_w        = (const float*)d_in[10];
  const float* out_b        = (const float*)d_in[11];
  const float* alpha_logits = (const float*)d_in[12];
  float* ws   = (float*)d_ws;
  float* outp = (float*)d_out;

  hipLaunchKernelGGL(k_tab, dim3(17), dim3(256), 0, stream,
                     embed, w1, b1, w2, b2, ln_g, ln_b,
                     rp_w, rp_b, out_w, out_b, alpha_logits, ws);
  hipLaunchKernelGGL(k_gw, dim3(V_SZ), dim3(64), 0, stream, ws);
  hipLaunchKernelGGL(k_scan, dim3(B_SZ / 64), dim3(256), 0, stream,
                     seq, ws, outp);
}